// Round 7
// baseline (993.791 us; speedup 1.0000x reference)
//
#include <hip/hip_runtime.h>
#include <stdint.h>

#define B_N 16384
#define D_N 1024
#define H_N 4096

typedef int i32x4 __attribute__((ext_vector_type(4)));
typedef int i32x8 __attribute__((ext_vector_type(8)));
typedef float f32x4 __attribute__((ext_vector_type(4)));

__device__ __forceinline__ void gload16(const void* g, void* l) {
  __builtin_amdgcn_global_load_lds((const __attribute__((address_space(1))) void*)g,
                                   (__attribute__((address_space(3))) void*)l,
                                   16, 0, 0);
}

__device__ __forceinline__ unsigned char f2fp8(float v) {
  return (unsigned char)(__builtin_amdgcn_cvt_pk_fp8_f32(v, v, 0, false) & 0xFF);
}

// within-64-block H permutation used for Dh stores / W2T K-index
__device__ __forceinline__ int perm_h(int h) {
  return (h & ~63) | ((h & 15) << 2) | ((h >> 4) & 3);
}

// ---- manual grid barrier (all 1024 blocks co-resident by launch_bounds) ----
// release: flush this XCD's L2 so phase outputs reach LLC; acquire: invalidate
// so stale lines are refetched. Counter monotonically increases per phase.
__device__ __forceinline__ void grid_barrier(int* cnt, int target) {
  __syncthreads();                 // all waves' stores issued (vmcnt drained)
  __threadfence();                 // device-scope release (L2 writeback)
  if (threadIdx.x == 0) {
    __hip_atomic_fetch_add(cnt, 1, __ATOMIC_RELEASE, __HIP_MEMORY_SCOPE_AGENT);
    while (__hip_atomic_load(cnt, __ATOMIC_ACQUIRE, __HIP_MEMORY_SCOPE_AGENT) < target)
      __builtin_amdgcn_s_sleep(8);
  }
  __syncthreads();
  __threadfence();                 // device-scope acquire (cache invalidate)
}

// ---- transpose 32x32 tile via shared float tile (aliases As) ----
__device__ __forceinline__ void transpose_tile(
    const float* __restrict__ in, unsigned char* __restrict__ out,
    int R, int C, float scale, float* __restrict__ w3, int pci,
    int i0, int j0, int tx, int ty, bool permute, float* tile /*32*33*/) {
#pragma unroll
  for (int r = 0; r < 32; r += 8) {
    int i = i0 + ty + r;
    int j = j0 + tx;
    float v = in[(size_t)i * C + j];
    tile[(ty + r) * 33 + tx] = v;
    if (w3 != nullptr && i == pci) w3[j] = v;
  }
  __syncthreads();
#pragma unroll
  for (int r = 0; r < 32; r += 8) {
    int jo = j0 + ty + r;
    int io = i0 + tx;
    int ioo = permute ? perm_h(io) : io;
    out[(size_t)jo * R + ioo] = f2fp8(tile[tx * 33 + ty + r] * scale);
  }
  __syncthreads();  // tile reused next iteration
}

// ---- MX-fp8 K=128 main loop (register-lean; XOR-swizzled LDS) ----
template <int KTOT>
__device__ __forceinline__ void mx_mainloop(
    const unsigned char* __restrict__ A, const unsigned char* __restrict__ B,
    int m0, int n0, int sa, int sb,
    unsigned char* As, unsigned char* Bs, f32x4 (&acc)[4][4]) {
  const int tid = threadIdx.x;
  const int lane = tid & 63;
  const int wave = tid >> 6;
  const int wm = (wave >> 1) * 64;
  const int wn = (wave & 1) * 64;
  const int lm = lane & 15;
  const int quad = lane >> 4;

  const int srow = tid >> 3;
  const int clog = (tid & 7) ^ (srow & 7);
  const unsigned char* Ag = A + (size_t)(m0 + srow) * KTOT + clog * 16;
  const unsigned char* Bg = B + (size_t)(n0 + srow) * KTOT + clog * 16;
  unsigned char* As_l = As + tid * 16;
  unsigned char* Bs_l = Bs + tid * 16;

  for (int k0 = 0; k0 < KTOT; k0 += 128) {
#pragma unroll
    for (int it = 0; it < 4; it++) {
      gload16(Ag + k0 + (size_t)(32 * it) * KTOT, As_l + it * 4096);
      gload16(Bg + k0 + (size_t)(32 * it) * KTOT, Bs_l + it * 4096);
    }
    __syncthreads();
    i32x8 b[4];
#pragma unroll
    for (int j = 0; j < 4; j++) {
      int r = wn + j * 16 + lm;
      int e = r & 7;
      i32x4 lo = *(const i32x4*)&Bs[r * 128 + ((2 * quad) ^ e) * 16];
      i32x4 hi = *(const i32x4*)&Bs[r * 128 + ((2 * quad + 1) ^ e) * 16];
      b[j] = __builtin_shufflevector(lo, hi, 0, 1, 2, 3, 4, 5, 6, 7);
    }
#pragma unroll
    for (int i = 0; i < 4; i++) {
      int r = wm + i * 16 + lm;
      int e = r & 7;
      i32x4 lo = *(const i32x4*)&As[r * 128 + ((2 * quad) ^ e) * 16];
      i32x4 hi = *(const i32x4*)&As[r * 128 + ((2 * quad + 1) ^ e) * 16];
      i32x8 av = __builtin_shufflevector(lo, hi, 0, 1, 2, 3, 4, 5, 6, 7);
#pragma unroll
      for (int j = 0; j < 4; j++)
        acc[i][j] = __builtin_amdgcn_mfma_scale_f32_16x16x128_f8f6f4(
            av, b[j], acc[i][j], 0, 0, 0, sa, 0, sb);
    }
    __syncthreads();
  }
}

// ================== fused kernel: prep | gemm1 | gemm2 (manual barriers) ====
// grid = 1024 blocks, 4/CU co-resident by __launch_bounds__(256,4):
// 128 regs (r5 measured 64 VGPR + 64 AGPR), 32.8 KB LDS -> 4 blocks/CU exact.
__global__ __launch_bounds__(256, 4) void fused_kernel(
    const float4* __restrict__ X4, unsigned char* __restrict__ Xb,
    float* __restrict__ s,
    const float* __restrict__ W1, unsigned char* __restrict__ W1T,
    float* __restrict__ w3,
    const float* __restrict__ W2, unsigned char* __restrict__ W2T,
    const int* __restrict__ pci_p, const float* __restrict__ b1,
    unsigned char* __restrict__ Dh, int* __restrict__ bar,
    float* __restrict__ out) {
  __shared__ alignas(16) unsigned char As[128 * 128];
  __shared__ alignas(16) unsigned char Bs[128 * 128];
  __shared__ float wsum[4];

  const int bid = blockIdx.x;        // 0..1023
  const int tid = threadIdx.x;
  const int pci = *pci_p;

  // ---------- phase 0: prep (16 virtual blocks each) ----------
  if (bid == 0 && tid == 0)          // device-scope store: lands at LLC
    __hip_atomic_store(out, 0.0f, __ATOMIC_RELAXED, __HIP_MEMORY_SCOPE_AGENT);
#pragma unroll 1
  for (int u = 0; u < 16; u++) {
    int vb = u * 1024 + bid;
    if (vb < 8192) {
      int i = (vb * 256 + tid) * 2;
#pragma unroll
      for (int v2 = 0; v2 < 2; v2++) {
        float4 v = X4[i + v2];
        int p = __builtin_amdgcn_cvt_pk_fp8_f32(v.x, v.y, 0, false);
        p = __builtin_amdgcn_cvt_pk_fp8_f32(v.z, v.w, p, true);
        ((int*)Xb)[i + v2] = p;
        if (((i + v2) & (D_N / 4 - 1)) == (pci >> 2)) {
          int row = (i + v2) >> 8;
          float c;
          switch (pci & 3) {
            case 0:  c = v.x; break;
            case 1:  c = v.y; break;
            case 2:  c = v.z; break;
            default: c = v.w; break;
          }
          s[row] = 1.0f - 2.0f * c;
        }
      }
    } else if (vb < 12288) {
      int id = vb - 8192;   // W1 (D_N x H_N) -> W1T[h][d]*16, h NOT permuted
      transpose_tile(W1, W1T, D_N, H_N, 16.0f, w3, pci,
                     (id >> 7) * 32, (id & 127) * 32, tid & 31, tid >> 5,
                     false, (float*)As);
    } else {
      int id = vb - 12288;  // W2 (H_N x D_N) -> W2T[d][perm(h)]*64
      transpose_tile(W2, W2T, H_N, D_N, 64.0f, nullptr, -1,
                     (id >> 5) * 32, (id & 31) * 32, tid & 31, tid >> 5,
                     true, (float*)As);
    }
  }
  grid_barrier(bar, 1024);

  // ---------- phase 1: gemm1, 4 tiles/block, fixed (m,ni), sweep nc --------
  // Reproduces r5's schedule: l = bid+1024*nc -> x=bid&7 (XCD), ni=(bid>>3)&7,
  // m=bid>>6. A-panel stays on this block/XCD across the nc sweep.
  {
    const int x = bid & 7;
    const int ni = (bid >> 3) & 7;
    const int m = bid >> 6;
    const int m0 = (x * 16 + m) * 128;
    const int lane = tid & 63;
    const int wave = tid >> 6;
    const int wm = (wave >> 1) * 64;
    const int wn = (wave & 1) * 64;
    const int lm = lane & 15;
    const int quad = lane >> 4;
#pragma unroll 1
    for (int nc = 0; nc < 4; nc++) {
      const int n0 = (nc * 8 + ni) * 128;
      f32x4 acc[4][4] = {};
      mx_mainloop<D_N>(Xb, W1T, m0, n0, 127, 123, As, Bs, acc);  // 2^0 * 2^-4

      float ewp[4], ewm[4], nump[4], numm[4], b1v[4];
#pragma unroll
      for (int j = 0; j < 4; j++) {
        int gh = n0 + wn + j * 16 + lm;
        float w = w3[gh];
        float ep = __expf(2.0f * w);
        float em = __expf(-2.0f * w);
        ewp[j] = ep; ewm[j] = em;
        nump[j] = 128.0f * (1.0f - ep);
        numm[j] = 128.0f * (1.0f - em);
        b1v[j] = b1[gh];
      }
      const size_t coloff = (size_t)((n0 + wn) >> 2) + lm;
#pragma unroll
      for (int i = 0; i < 4; i++) {
#pragma unroll
        for (int r = 0; r < 4; r++) {
          int gb = m0 + wm + i * 16 + quad * 4 + r;
          bool sp = s[gb] > 0.0f;
          float o[4];
#pragma unroll
          for (int j = 0; j < 4; j++) {
            float ews = sp ? ewp[j] : ewm[j];
            float num = sp ? nump[j] : numm[j];
            float z = fminf(acc[i][j][r] + b1v[j], 12.0f);
            float E = __expf(2.0f * z);
            float den = (E * ews + 1.0f) * (E + 1.0f);
            o[j] = (E * num) * __builtin_amdgcn_rcpf(den);  // 64*dh
          }
          int p = __builtin_amdgcn_cvt_pk_fp8_f32(o[0], o[1], 0, false);
          p = __builtin_amdgcn_cvt_pk_fp8_f32(o[2], o[3], p, true);
          ((unsigned int*)Dh)[(size_t)gb * (H_N / 4) + coloff] = (unsigned int)p;
        }
      }
    }
  }
  grid_barrier(bar, 2048);

  // ---------- phase 2: gemm2, 1 tile/block (same m<->XCD map as phase 1) ---
  {
    const int x = bid & 7;
    const int k = bid >> 3;
    const int c = k >> 6;
    const int idx = k & 63;
    const int m = idx >> 2;
    const int nj = idx & 3;
    const int m0 = (x * 16 + m) * 128;
    const int n0 = (c * 4 + nj) * 128;

    f32x4 acc[4][4] = {};
    mx_mainloop<H_N>(Dh, W2T, m0, n0, 121, 121, As, Bs, acc);  // 2^-6 * 2^-6

    const int lane = tid & 63;
    const int wave = tid >> 6;
    float t = 0.0f;
#pragma unroll
    for (int i = 0; i < 4; i++)
#pragma unroll
      for (int j = 0; j < 4; j++)
#pragma unroll
        for (int r = 0; r < 4; r++)
          t += fabsf(acc[i][j][r]);

#pragma unroll
    for (int off2 = 32; off2 > 0; off2 >>= 1)
      t += __shfl_down(t, off2, 64);
    if (lane == 0) wsum[wave] = t;
    __syncthreads();
    if (tid == 0)
      atomicAdd(out, (wsum[0] + wsum[1] + wsum[2] + wsum[3]) * (1.0f / (float)B_N));
  }
}

extern "C" void kernel_launch(void* const* d_in, const int* in_sizes, int n_in,
                              void* d_out, int out_size, void* d_ws, size_t ws_size,
                              hipStream_t stream) {
  const float* X  = (const float*)d_in[0];
  const float* W1 = (const float*)d_in[1];
  const float* b1 = (const float*)d_in[2];
  const float* W2 = (const float*)d_in[3];
  // d_in[4] = b2 : cancels in the difference
  const int* pci  = (const int*)d_in[5];

  char* ws = (char*)d_ws;
  size_t off = 0;
  unsigned char* Xb  = (unsigned char*)(ws + off); off += (size_t)B_N * D_N;
  unsigned char* W1T = (unsigned char*)(ws + off); off += (size_t)H_N * D_N;
  unsigned char* W2T = (unsigned char*)(ws + off); off += (size_t)D_N * H_N;
  float* w3  = (float*)(ws + off); off += (size_t)H_N * 4;
  float* s   = (float*)(ws + off); off += (size_t)B_N * 4;
  unsigned char* Dh  = (unsigned char*)(ws + off); off += (size_t)B_N * H_N;
  int* bar = (int*)(ws + off); off += 256;
  if (ws_size < off) return;

  hipMemsetAsync(bar, 0, sizeof(int), stream);
  fused_kernel<<<1024, 256, 0, stream>>>(
      (const float4*)X, Xb, s, W1, W1T, w3, W2, W2T, pci, b1, Dh, bar,
      (float*)d_out);
}

// Round 8
// 470.413 us; speedup vs baseline: 2.1126x; 2.1126x over previous
//
#include <hip/hip_runtime.h>
#include <stdint.h>

#define B_N 16384
#define D_N 1024
#define H_N 4096

typedef int i32x4 __attribute__((ext_vector_type(4)));
typedef int i32x8 __attribute__((ext_vector_type(8)));
typedef float f32x4 __attribute__((ext_vector_type(4)));

__device__ __forceinline__ void gload16(const void* g, void* l) {
  __builtin_amdgcn_global_load_lds((const __attribute__((address_space(1))) void*)g,
                                   (__attribute__((address_space(3))) void*)l,
                                   16, 0, 0);
}

// device-scope (sc1, write-through-to-LLC) stores: no dirty L2 lines ever.
__device__ __forceinline__ void st_agent_u32(unsigned int* p, unsigned int v) {
  __hip_atomic_store(p, v, __ATOMIC_RELAXED, __HIP_MEMORY_SCOPE_AGENT);
}
__device__ __forceinline__ void st_agent_f32(float* p, float v) {
  __hip_atomic_store(p, v, __ATOMIC_RELAXED, __HIP_MEMORY_SCOPE_AGENT);
}

__device__ __forceinline__ unsigned int pack4_fp8(float a, float b, float c, float d) {
  int p = __builtin_amdgcn_cvt_pk_fp8_f32(a, b, 0, false);
  p = __builtin_amdgcn_cvt_pk_fp8_f32(c, d, p, true);
  return (unsigned int)p;
}

// ---- fence-free grid barrier ----
// All producer stores are sc1 (LLC-visible once vmcnt drains). __syncthreads
// drains vmcnt per wave, so a relaxed agent add is a correct release; relaxed
// agent spin-load is a correct acquire because consumer caches hold no stale
// copies of never-before-read lines. NO buffer_wbl2 / buffer_inv (r7's 700us).
__device__ __forceinline__ void grid_barrier(int* cnt, int target) {
  __syncthreads();
  if (threadIdx.x == 0) {
    __hip_atomic_fetch_add(cnt, 1, __ATOMIC_RELAXED, __HIP_MEMORY_SCOPE_AGENT);
    while (__hip_atomic_load(cnt, __ATOMIC_RELAXED, __HIP_MEMORY_SCOPE_AGENT) < target)
      __builtin_amdgcn_s_sleep(2);
  }
  __syncthreads();
}

// ---- MX-fp8 K=128 main loop (register-lean; XOR-swizzled LDS) ----
template <int KTOT>
__device__ __forceinline__ void mx_mainloop(
    const unsigned char* __restrict__ A, const unsigned char* __restrict__ B,
    int m0, int n0, int sa, int sb,
    unsigned char* As, unsigned char* Bs, f32x4 (&acc)[4][4]) {
  const int tid = threadIdx.x;
  const int lane = tid & 63;
  const int wave = tid >> 6;
  const int wm = (wave >> 1) * 64;
  const int wn = (wave & 1) * 64;
  const int lm = lane & 15;
  const int quad = lane >> 4;

  const int srow = tid >> 3;
  const int clog = (tid & 7) ^ (srow & 7);
  const unsigned char* Ag = A + (size_t)(m0 + srow) * KTOT + clog * 16;
  const unsigned char* Bg = B + (size_t)(n0 + srow) * KTOT + clog * 16;
  unsigned char* As_l = As + tid * 16;
  unsigned char* Bs_l = Bs + tid * 16;

  for (int k0 = 0; k0 < KTOT; k0 += 128) {
#pragma unroll
    for (int it = 0; it < 4; it++) {
      gload16(Ag + k0 + (size_t)(32 * it) * KTOT, As_l + it * 4096);
      gload16(Bg + k0 + (size_t)(32 * it) * KTOT, Bs_l + it * 4096);
    }
    __syncthreads();
    i32x8 b[4];
#pragma unroll
    for (int j = 0; j < 4; j++) {
      int r = wn + j * 16 + lm;
      int e = r & 7;
      i32x4 lo = *(const i32x4*)&Bs[r * 128 + ((2 * quad) ^ e) * 16];
      i32x4 hi = *(const i32x4*)&Bs[r * 128 + ((2 * quad + 1) ^ e) * 16];
      b[j] = __builtin_shufflevector(lo, hi, 0, 1, 2, 3, 4, 5, 6, 7);
    }
#pragma unroll
    for (int i = 0; i < 4; i++) {
      int r = wm + i * 16 + lm;
      int e = r & 7;
      i32x4 lo = *(const i32x4*)&As[r * 128 + ((2 * quad) ^ e) * 16];
      i32x4 hi = *(const i32x4*)&As[r * 128 + ((2 * quad + 1) ^ e) * 16];
      i32x8 av = __builtin_shufflevector(lo, hi, 0, 1, 2, 3, 4, 5, 6, 7);
#pragma unroll
      for (int j = 0; j < 4; j++)
        acc[i][j] = __builtin_amdgcn_mfma_scale_f32_16x16x128_f8f6f4(
            av, b[j], acc[i][j], 0, 0, 0, sa, 0, sb);
    }
    __syncthreads();
  }
}

// ================== fused kernel: prep | gemm1 | gemm2 ======================
// grid = 1024 blocks, 4/CU co-resident (proven in r7: barrier completed,
// occupancy ~48%). All inter-phase stores sc1; barriers fence-free.
__global__ __launch_bounds__(256, 4) void fused_kernel(
    const float4* __restrict__ X4, unsigned char* __restrict__ Xb,
    float* __restrict__ s,
    const float* __restrict__ W1, unsigned char* __restrict__ W1T,
    float* __restrict__ w3,
    const float* __restrict__ W2, unsigned char* __restrict__ W2T,
    const int* __restrict__ pci_p, const float* __restrict__ b1,
    unsigned char* __restrict__ Dh, int* __restrict__ bar,
    float* __restrict__ out) {
  __shared__ alignas(16) unsigned char As[128 * 128];
  __shared__ alignas(16) unsigned char Bs[128 * 128];
  __shared__ float wsum[4];

  const int bid = blockIdx.x;        // 0..1023
  const int tid = threadIdx.x;
  const int pci = *pci_p;

  // ---------------- phase 0: prep ----------------
  if (bid == 0 && tid == 0) st_agent_f32(out, 0.0f);

  // X pack: 8 chunks/block, 2 float4/thread/chunk
#pragma unroll 1
  for (int u = 0; u < 8; u++) {
    int vb = bid * 8 + u;
    int i = (vb * 256 + tid) * 2;
#pragma unroll
    for (int v2 = 0; v2 < 2; v2++) {
      float4 v = X4[i + v2];
      st_agent_u32(&((unsigned int*)Xb)[i + v2],
                   pack4_fp8(v.x, v.y, v.z, v.w));
      if (((i + v2) & (D_N / 4 - 1)) == (pci >> 2)) {
        int row = (i + v2) >> 8;
        float c;
        switch (pci & 3) {
          case 0:  c = v.x; break;
          case 1:  c = v.y; break;
          case 2:  c = v.z; break;
          default: c = v.w; break;
        }
        st_agent_f32(&s[row], 1.0f - 2.0f * c);
      }
    }
  }

  // W1 (D_N x H_N) -> W1T[h][d] = W1[d][h]*16 ; 32x32 tiles, 4 jobs/block;
  // output packed 4 bytes (4 consecutive d) per thread -> dword sc1 stores.
  {
    float* tile = (float*)As;                 // [32][33]
    const int tx = tid & 31, ty = tid >> 5;   // load coords
    const int hl = tid >> 3, g = tid & 7;     // store coords
#pragma unroll 1
    for (int u = 0; u < 4; u++) {
      int id = bid * 4 + u;
      int d0 = (id >> 7) * 32, h0 = (id & 127) * 32;
      __syncthreads();
#pragma unroll
      for (int r = 0; r < 32; r += 8) {
        float v = W1[(size_t)(d0 + ty + r) * H_N + h0 + tx];
        tile[(ty + r) * 33 + tx] = v;
        if (d0 + ty + r == pci) st_agent_f32(&w3[h0 + tx], v);
      }
      __syncthreads();
      unsigned int p = pack4_fp8(tile[(4 * g + 0) * 33 + hl] * 16.0f,
                                 tile[(4 * g + 1) * 33 + hl] * 16.0f,
                                 tile[(4 * g + 2) * 33 + hl] * 16.0f,
                                 tile[(4 * g + 3) * 33 + hl] * 16.0f);
      st_agent_u32(&((unsigned int*)W1T)[(size_t)(h0 + hl) * (D_N / 4) +
                                         (d0 >> 2) + g], p);
    }
  }

  // W2 (H_N x D_N) -> W2T[d][perm(h)] = W2[h][d]*64 ; 64h x 32d tiles,
  // 2 jobs/block. perm(16b+a) = 4a+b within 64-blocks, so output uint
  // (d, h0+4a..4a+3) gathers LDS rows {a,16+a,32+a,48+a}, col d. sc1 dwords.
  {
    float* tile = (float*)As;                 // [64][33]
#pragma unroll 1
    for (int u = 0; u < 2; u++) {
      int id = bid * 2 + u;
      int h0 = (id >> 5) * 64, d0 = (id & 31) * 32;
      __syncthreads();
#pragma unroll
      for (int r = 0; r < 8; r++) {
        int hh = (tid >> 5) + 8 * r;
        int dd = tid & 31;
        tile[hh * 33 + dd] = W2[(size_t)(h0 + hh) * D_N + d0 + dd];
      }
      __syncthreads();
#pragma unroll
      for (int w = 0; w < 2; w++) {
        int idx = tid + 256 * w;
        int d = idx >> 4, a = idx & 15;
        unsigned int p = pack4_fp8(tile[(a)      * 33 + d] * 64.0f,
                                   tile[(16 + a) * 33 + d] * 64.0f,
                                   tile[(32 + a) * 33 + d] * 64.0f,
                                   tile[(48 + a) * 33 + d] * 64.0f);
        st_agent_u32(&((unsigned int*)W2T)[(size_t)(d0 + d) * (H_N / 4) +
                                           (h0 >> 2) + a], p);
      }
    }
  }
  grid_barrier(bar, 1024);

  // ---------- phase 1: gemm1, 4 tiles/block, fixed (m,ni), sweep nc --------
  // r5 schedule: x=bid&7 (XCD), ni=(bid>>3)&7, m=bid>>6; n0=(nc*8+ni)*128.
  {
    const int x = bid & 7;
    const int ni = (bid >> 3) & 7;
    const int m = bid >> 6;
    const int m0 = (x * 16 + m) * 128;
    const int lane = tid & 63;
    const int wave = tid >> 6;
    const int wm = (wave >> 1) * 64;
    const int wn = (wave & 1) * 64;
    const int lm = lane & 15;
    const int quad = lane >> 4;
#pragma unroll 1
    for (int nc = 0; nc < 4; nc++) {
      const int n0 = (nc * 8 + ni) * 128;
      f32x4 acc[4][4] = {};
      mx_mainloop<D_N>(Xb, W1T, m0, n0, 127, 123, As, Bs, acc);  // 2^0 * 2^-4

      float ewp[4], ewm[4], nump[4], numm[4], b1v[4];
#pragma unroll
      for (int j = 0; j < 4; j++) {
        int gh = n0 + wn + j * 16 + lm;
        float w = w3[gh];
        float ep = __expf(2.0f * w);
        float em = __expf(-2.0f * w);
        ewp[j] = ep; ewm[j] = em;
        nump[j] = 128.0f * (1.0f - ep);
        numm[j] = 128.0f * (1.0f - em);
        b1v[j] = b1[gh];
      }
      const size_t coloff = (size_t)((n0 + wn) >> 2) + lm;
#pragma unroll
      for (int i = 0; i < 4; i++) {
#pragma unroll
        for (int r = 0; r < 4; r++) {
          int gb = m0 + wm + i * 16 + quad * 4 + r;
          bool sp = s[gb] > 0.0f;
          float o[4];
#pragma unroll
          for (int j = 0; j < 4; j++) {
            float ews = sp ? ewp[j] : ewm[j];
            float num = sp ? nump[j] : numm[j];
            float z = fminf(acc[i][j][r] + b1v[j], 12.0f);
            float E = __expf(2.0f * z);
            float den = (E * ews + 1.0f) * (E + 1.0f);
            o[j] = (E * num) * __builtin_amdgcn_rcpf(den);  // 64*dh
          }
          st_agent_u32(&((unsigned int*)Dh)[(size_t)gb * (H_N / 4) + coloff],
                       pack4_fp8(o[0], o[1], o[2], o[3]));
        }
      }
    }
  }
  grid_barrier(bar, 2048);

  // ---------- phase 2: gemm2, 1 tile/block (same m<->XCD map) --------------
  {
    const int x = bid & 7;
    const int k = bid >> 3;
    const int c = k >> 6;
    const int idx = k & 63;
    const int m = idx >> 2;
    const int nj = idx & 3;
    const int m0 = (x * 16 + m) * 128;
    const int n0 = (c * 4 + nj) * 128;

    f32x4 acc[4][4] = {};
    mx_mainloop<H_N>(Dh, W2T, m0, n0, 121, 121, As, Bs, acc);  // 2^-6 * 2^-6

    const int lane = tid & 63;
    const int wave = tid >> 6;
    float t = 0.0f;
#pragma unroll
    for (int i = 0; i < 4; i++)
#pragma unroll
      for (int j = 0; j < 4; j++)
#pragma unroll
        for (int r = 0; r < 4; r++)
          t += fabsf(acc[i][j][r]);

#pragma unroll
    for (int off2 = 32; off2 > 0; off2 >>= 1)
      t += __shfl_down(t, off2, 64);
    if (lane == 0) wsum[wave] = t;
    __syncthreads();
    if (tid == 0)
      __hip_atomic_fetch_add(out,
          (wsum[0] + wsum[1] + wsum[2] + wsum[3]) * (1.0f / (float)B_N),
          __ATOMIC_RELAXED, __HIP_MEMORY_SCOPE_AGENT);
  }
}

extern "C" void kernel_launch(void* const* d_in, const int* in_sizes, int n_in,
                              void* d_out, int out_size, void* d_ws, size_t ws_size,
                              hipStream_t stream) {
  const float* X  = (const float*)d_in[0];
  const float* W1 = (const float*)d_in[1];
  const float* b1 = (const float*)d_in[2];
  const float* W2 = (const float*)d_in[3];
  // d_in[4] = b2 : cancels in the difference
  const int* pci  = (const int*)d_in[5];

  char* ws = (char*)d_ws;
  size_t off = 0;
  unsigned char* Xb  = (unsigned char*)(ws + off); off += (size_t)B_N * D_N;
  unsigned char* W1T = (unsigned char*)(ws + off); off += (size_t)H_N * D_N;
  unsigned char* W2T = (unsigned char*)(ws + off); off += (size_t)D_N * H_N;
  float* w3  = (float*)(ws + off); off += (size_t)H_N * 4;
  float* s   = (float*)(ws + off); off += (size_t)B_N * 4;
  unsigned char* Dh  = (unsigned char*)(ws + off); off += (size_t)B_N * H_N;
  int* bar = (int*)(ws + off); off += 256;
  if (ws_size < off) return;

  hipMemsetAsync(bar, 0, sizeof(int), stream);
  fused_kernel<<<1024, 256, 0, stream>>>(
      (const float4*)X, Xb, s, W1, W1T, w3, W2, W2T, pci, b1, Dh, bar,
      (float*)d_out);
}

// Round 9
// 360.272 us; speedup vs baseline: 2.7584x; 1.3057x over previous
//
#include <hip/hip_runtime.h>
#include <stdint.h>

#define B_N 16384
#define D_N 1024
#define H_N 4096

typedef int i32x4 __attribute__((ext_vector_type(4)));
typedef int i32x8 __attribute__((ext_vector_type(8)));
typedef float f32x4 __attribute__((ext_vector_type(4)));
typedef unsigned int u32x4 __attribute__((ext_vector_type(4)));

__device__ __forceinline__ void gload16(const void* g, void* l) {
  __builtin_amdgcn_global_load_lds((const __attribute__((address_space(1))) void*)g,
                                   (__attribute__((address_space(3))) void*)l,
                                   16, 0, 0);
}

__device__ __forceinline__ unsigned char f2fp8(float v) {
  return (unsigned char)(__builtin_amdgcn_cvt_pk_fp8_f32(v, v, 0, false) & 0xFF);
}

// within-64-block H permutation used for Dh stores / W2T K-index
__device__ __forceinline__ int perm_h(int h) {
  return (h & ~63) | ((h & 15) << 2) | ((h >> 4) & 3);
}

// ================= prep (own dispatch; plain cached stores — the dispatch
// boundary provides cross-XCD visibility, proven r3-r5). Zeroes out + cnt. ===
__device__ __forceinline__ void transpose_tile(
    const float* __restrict__ in, unsigned char* __restrict__ out,
    int R, int C, float scale, float* __restrict__ w3, int pci,
    int i0, int j0, int tx, int ty, bool permute) {
  __shared__ float tile[32][33];
#pragma unroll
  for (int r = 0; r < 32; r += 8) {
    int i = i0 + ty + r;
    int j = j0 + tx;
    float v = in[(size_t)i * C + j];
    tile[ty + r][tx] = v;
    if (w3 != nullptr && i == pci) w3[j] = v;
  }
  __syncthreads();
#pragma unroll
  for (int r = 0; r < 32; r += 8) {
    int jo = j0 + ty + r;
    int io = i0 + tx;
    int ioo = permute ? perm_h(io) : io;
    out[(size_t)jo * R + ioo] = f2fp8(tile[tx][ty + r] * scale);
  }
}

__global__ __launch_bounds__(256) void prep_kernel(
    const float4* __restrict__ X4, int* __restrict__ Xb,
    float* __restrict__ s,
    const float* __restrict__ W1, unsigned char* __restrict__ W1T,
    float* __restrict__ w3,
    const float* __restrict__ W2, unsigned char* __restrict__ W2T,
    const int* __restrict__ pci_p, int* __restrict__ cnt,
    float* __restrict__ out0) {
  int b = blockIdx.x;
  int tid = threadIdx.x;
  int pci = *pci_p;
  if (b == 0) {
    if (tid < 128) cnt[tid] = 0;
    if (tid == 0) out0[0] = 0.0f;
  }
  if (b < 8192) {
    int i = (b * 256 + tid) * 2;
#pragma unroll
    for (int u = 0; u < 2; u++) {
      float4 v = X4[i + u];
      int p = __builtin_amdgcn_cvt_pk_fp8_f32(v.x, v.y, 0, false);
      p = __builtin_amdgcn_cvt_pk_fp8_f32(v.z, v.w, p, true);
      Xb[i + u] = p;
      if (((i + u) & (D_N / 4 - 1)) == (pci >> 2)) {
        int row = (i + u) >> 8;
        float c;
        switch (pci & 3) {
          case 0:  c = v.x; break;
          case 1:  c = v.y; break;
          case 2:  c = v.z; break;
          default: c = v.w; break;
        }
        s[row] = 1.0f - 2.0f * c;
      }
    }
  } else if (b < 12288) {
    int id = b - 8192;   // W1 (D_N x H_N) -> W1T[h][d]*16, h NOT permuted
    transpose_tile(W1, W1T, D_N, H_N, 16.0f, w3, pci,
                   (id >> 7) * 32, (id & 127) * 32, tid & 31, tid >> 5, false);
  } else {
    int id = b - 12288;  // W2 (H_N x D_N) -> W2T[d][perm(h)]*64
    transpose_tile(W2, W2T, H_N, D_N, 64.0f, nullptr, -1,
                   (id >> 5) * 32, (id & 31) * 32, tid & 31, tid >> 5, true);
  }
}

// ---- MX-fp8 K=128 main loop (register-lean; XOR-swizzled LDS) ----
template <int KTOT>
__device__ __forceinline__ void mx_mainloop(
    const unsigned char* __restrict__ A, const unsigned char* __restrict__ B,
    int m0, int n0, int sa, int sb,
    unsigned char* As, unsigned char* Bs, f32x4 (&acc)[4][4]) {
  const int tid = threadIdx.x;
  const int lane = tid & 63;
  const int wave = tid >> 6;
  const int wm = (wave >> 1) * 64;
  const int wn = (wave & 1) * 64;
  const int lm = lane & 15;
  const int quad = lane >> 4;

  const int srow = tid >> 3;
  const int clog = (tid & 7) ^ (srow & 7);
  const unsigned char* Ag = A + (size_t)(m0 + srow) * KTOT + clog * 16;
  const unsigned char* Bg = B + (size_t)(n0 + srow) * KTOT + clog * 16;
  unsigned char* As_l = As + tid * 16;
  unsigned char* Bs_l = Bs + tid * 16;

  for (int k0 = 0; k0 < KTOT; k0 += 128) {
#pragma unroll
    for (int it = 0; it < 4; it++) {
      gload16(Ag + k0 + (size_t)(32 * it) * KTOT, As_l + it * 4096);
      gload16(Bg + k0 + (size_t)(32 * it) * KTOT, Bs_l + it * 4096);
    }
    __syncthreads();
    i32x8 b[4];
#pragma unroll
    for (int j = 0; j < 4; j++) {
      int r = wn + j * 16 + lm;
      int e = r & 7;
      i32x4 lo = *(const i32x4*)&Bs[r * 128 + ((2 * quad) ^ e) * 16];
      i32x4 hi = *(const i32x4*)&Bs[r * 128 + ((2 * quad + 1) ^ e) * 16];
      b[j] = __builtin_shufflevector(lo, hi, 0, 1, 2, 3, 4, 5, 6, 7);
    }
#pragma unroll
    for (int i = 0; i < 4; i++) {
      int r = wm + i * 16 + lm;
      int e = r & 7;
      i32x4 lo = *(const i32x4*)&As[r * 128 + ((2 * quad) ^ e) * 16];
      i32x4 hi = *(const i32x4*)&As[r * 128 + ((2 * quad + 1) ^ e) * 16];
      i32x8 av = __builtin_shufflevector(lo, hi, 0, 1, 2, 3, 4, 5, 6, 7);
#pragma unroll
      for (int j = 0; j < 4; j++)
        acc[i][j] = __builtin_amdgcn_mfma_scale_f32_16x16x128_f8f6f4(
            av, b[j], acc[i][j], 0, 0, 0, sa, 0, sb);
    }
    __syncthreads();
  }
}

// ================== fused gemm kernel: gemm1 -> per-panel sync -> gemm2 =====
// grid = 1024 blocks, 4/CU co-resident (proven r7/r8). Dh crosses the sync
// via LDS-staged nontemporal uint4 stores (write-through, no dirty L2 lines,
// full-line coalesced) -> plain gload16 reads after the panel counter hits 32.
__global__ __launch_bounds__(256, 4) void fused_gemm(
    const unsigned char* __restrict__ Xb,    // B_N x D_N fp8 (x1)
    const unsigned char* __restrict__ W1T,   // H_N x D_N fp8 (x16)
    const float* __restrict__ b1,
    const float* __restrict__ w3,            // H_N : W1[pci][h]
    const float* __restrict__ s,             // B_N : 1-2*col
    unsigned char* __restrict__ Dh,          // B_N x H_N fp8 (x64), perm'd cols
    const unsigned char* __restrict__ W2T,   // D_N x H_N fp8 (x64), perm'd K
    int* __restrict__ cnt,                   // 128 panel counters (zeroed)
    float* __restrict__ out) {
  __shared__ alignas(16) unsigned char smem[32768];
  __shared__ float wsum[4];
  unsigned char* As = smem;
  unsigned char* Bs = smem + 16384;
  unsigned int* stage = (unsigned int*)smem;   // 128 rows x 36 dw (18.4 KB)

  const int bid = blockIdx.x;
  const int tid = threadIdx.x;
  const int lane = tid & 63;
  const int wave = tid >> 6;
  const int wm = (wave >> 1) * 64;
  const int wn = (wave & 1) * 64;
  const int lm = lane & 15;
  const int quad = lane >> 4;

  // ---------- phase 1: gemm1, 4 tiles (nc sweep), r5 schedule ----------
  {
    const int x = bid & 7;                    // XCD heuristic (perf only)
    const int ni = (bid >> 3) & 7;
    const int m = bid >> 6;
    const int m0 = (x * 16 + m) * 128;
    const int panel = x * 16 + m;
#pragma unroll 1
    for (int nc = 0; nc < 4; nc++) {
      const int n0 = (nc * 8 + ni) * 128;
      f32x4 acc[4][4] = {};
      mx_mainloop<D_N>(Xb, W1T, m0, n0, 127, 123, As, Bs, acc);  // 2^0 * 2^-4

      float ewp[4], ewm[4], nump[4], numm[4], b1v[4];
#pragma unroll
      for (int j = 0; j < 4; j++) {
        int gh = n0 + wn + j * 16 + lm;
        float w = w3[gh];
        float ep = __expf(2.0f * w);
        float em = __expf(-2.0f * w);
        ewp[j] = ep; ewm[j] = em;
        nump[j] = 128.0f * (1.0f - ep);
        numm[j] = 128.0f * (1.0f - em);
        b1v[j] = b1[gh];
      }
      const int scol = ((wn >> 2) & 31) + lm;   // tile col-dword 0..31
#pragma unroll
      for (int i = 0; i < 4; i++) {
#pragma unroll
        for (int r = 0; r < 4; r++) {
          int trow = wm + i * 16 + quad * 4 + r;   // tile row 0..127
          bool sp = s[m0 + trow] > 0.0f;
          float o[4];
#pragma unroll
          for (int j = 0; j < 4; j++) {
            float ews = sp ? ewp[j] : ewm[j];
            float num = sp ? nump[j] : numm[j];
            float z = fminf(acc[i][j][r] + b1v[j], 12.0f);
            float E = __expf(2.0f * z);
            float den = (E * ews + 1.0f) * (E + 1.0f);
            o[j] = (E * num) * __builtin_amdgcn_rcpf(den);  // 64*dh
          }
          int p = __builtin_amdgcn_cvt_pk_fp8_f32(o[0], o[1], 0, false);
          p = __builtin_amdgcn_cvt_pk_fp8_f32(o[2], o[3], p, true);
          stage[trow * 36 + scol] = (unsigned int)p;  // stride 36dw: 2-way banks
        }
      }
      __syncthreads();
      // LDS -> global: 1024 uint4, nontemporal (write-through, full lines)
#pragma unroll
      for (int w = 0; w < 4; w++) {
        int idx = tid + 256 * w;
        int row = idx >> 3, c = idx & 7;
        u32x4 v = *(const u32x4*)(stage + row * 36 + 4 * c);  // 144B stride: aligned
        __builtin_nontemporal_store(
            v, (u32x4*)Dh + (size_t)(m0 + row) * 256 + (n0 >> 4) + c);
      }
      __syncthreads();  // copy reads done before next tile's gloads; vmcnt drained
      if (tid == 0)
        __hip_atomic_fetch_add(&cnt[panel], 1, __ATOMIC_RELAXED,
                               __HIP_MEMORY_SCOPE_AGENT);
    }
  }

  // ---------- phase 2: gemm2, 1 tile, waits for its Dh panel (32 tiles) ----
  {
    const int x = bid & 7;
    const int k = bid >> 3;
    const int c = k >> 6;
    const int idx = k & 63;
    const int m = idx >> 2;
    const int nj = idx & 3;
    const int m0 = (x * 16 + m) * 128;
    const int n0 = (c * 4 + nj) * 128;
    const int panel = x * 16 + m;

    if (tid == 0)
      while (__hip_atomic_load(&cnt[panel], __ATOMIC_RELAXED,
                               __HIP_MEMORY_SCOPE_AGENT) < 32)
        __builtin_amdgcn_s_sleep(2);
    __syncthreads();

    f32x4 acc[4][4] = {};
    mx_mainloop<H_N>(Dh, W2T, m0, n0, 121, 121, As, Bs, acc);  // 2^-6 * 2^-6

    float t = 0.0f;
#pragma unroll
    for (int i = 0; i < 4; i++)
#pragma unroll
      for (int j = 0; j < 4; j++)
#pragma unroll
        for (int r = 0; r < 4; r++)
          t += fabsf(acc[i][j][r]);

#pragma unroll
    for (int off2 = 32; off2 > 0; off2 >>= 1)
      t += __shfl_down(t, off2, 64);
    if (lane == 0) wsum[wave] = t;
    __syncthreads();
    if (tid == 0)
      atomicAdd(out, (wsum[0] + wsum[1] + wsum[2] + wsum[3]) * (1.0f / (float)B_N));
  }
}

extern "C" void kernel_launch(void* const* d_in, const int* in_sizes, int n_in,
                              void* d_out, int out_size, void* d_ws, size_t ws_size,
                              hipStream_t stream) {
  const float* X  = (const float*)d_in[0];
  const float* W1 = (const float*)d_in[1];
  const float* b1 = (const float*)d_in[2];
  const float* W2 = (const float*)d_in[3];
  // d_in[4] = b2 : cancels in the difference
  const int* pci  = (const int*)d_in[5];

  char* ws = (char*)d_ws;
  size_t off = 0;
  unsigned char* Xb  = (unsigned char*)(ws + off); off += (size_t)B_N * D_N;
  unsigned char* W1T = (unsigned char*)(ws + off); off += (size_t)H_N * D_N;
  unsigned char* W2T = (unsigned char*)(ws + off); off += (size_t)D_N * H_N;
  float* w3  = (float*)(ws + off); off += (size_t)H_N * 4;
  float* s   = (float*)(ws + off); off += (size_t)B_N * 4;
  unsigned char* Dh  = (unsigned char*)(ws + off); off += (size_t)B_N * H_N;
  int* cnt = (int*)(ws + off); off += 512;
  if (ws_size < off) return;

  prep_kernel<<<16384, 256, 0, stream>>>((const float4*)X, (int*)Xb, s,
                                         W1, W1T, w3, W2, W2T, pci, cnt,
                                         (float*)d_out);
  fused_gemm<<<1024, 256, 0, stream>>>(Xb, W1T, b1, w3, s, Dh, W2T, cnt,
                                       (float*)d_out);
}